// Round 5
// baseline (140.190 us; speedup 1.0000x reference)
//
#include <hip/hip_runtime.h>
#include <hip/hip_fp16.h>

#define NS 256
#define N2 (NS * NS)          // 65536
#define HID 32
#define T_STEPS 64

typedef _Float16 h2     __attribute__((ext_vector_type(2)));
typedef _Float16 half8  __attribute__((ext_vector_type(8)));
typedef float    float4v __attribute__((ext_vector_type(4)));

__device__ __forceinline__ float eluf(float z) {
    // max(z, exp(min(z,0)) - 1): z>0 -> max(z,0)=z ; z<=0 -> exp(z)-1
    return fmaxf(z, __expf(fminf(z, 0.0f)) - 1.0f);
}

__device__ __forceinline__ h2 splat2(float f) {
    _Float16 h = (_Float16)f;
    h2 r; r[0] = h; r[1] = h;
    return r;
}

// packed-f16 ELU: max(z, exp2(min(z,0)*log2e) - 1)
__device__ __forceinline__ h2 elu2(h2 z) {
    h2 zero; zero[0] = (_Float16)0.f; zero[1] = (_Float16)0.f;
    h2 zm = __builtin_elementwise_min(z, zero);
    h2 e  = __builtin_elementwise_exp2(zm * (_Float16)1.442695041f);
    h2 em1 = e + (_Float16)(-1.0f);
    return __builtin_elementwise_max(z, em1);
}

__global__ __launch_bounds__(256, 4) void mlpconv_row_kernel(
    const float* __restrict__ x,
    const float* __restrict__ W0, const float* __restrict__ b0,
    const float* __restrict__ W1, const float* __restrict__ b1,
    const float* __restrict__ W2, const float* __restrict__ b2,
    float* __restrict__ out)
{
    const int lane = threadIdx.x & 63;
    const int m    = lane & 15;   // point within 16-pt tile / B col / C-D col
    const int kg   = lane >> 4;   // k-group

    // -------- weight preload, flat locals (kept register-resident) --------
    h2 w00, w01, w02, w03, w10, w11, w12, w13, w20, w21, w22, w23,
       w30, w31, w32, w33, w40, w41, w42, w43;
    {
        const int c0 = kg * 8;
        #define LW(c, v0, v1, v2, v3)                                   \
            v0[0] = (_Float16)W0[c * HID + c0 + 0];                     \
            v0[1] = (_Float16)W0[c * HID + c0 + 1];                     \
            v1[0] = (_Float16)W0[c * HID + c0 + 2];                     \
            v1[1] = (_Float16)W0[c * HID + c0 + 3];                     \
            v2[0] = (_Float16)W0[c * HID + c0 + 4];                     \
            v2[1] = (_Float16)W0[c * HID + c0 + 5];                     \
            v3[0] = (_Float16)W0[c * HID + c0 + 6];                     \
            v3[1] = (_Float16)W0[c * HID + c0 + 7];
        LW(0, w00, w01, w02, w03)
        LW(1, w10, w11, w12, w13)
        LW(2, w20, w21, w22, w23)
        LW(3, w30, w31, w32, w33)
        LW(4, w40, w41, w42, w43)
        #undef LW
    }
    h2 b00, b01, b02, b03;
    b00[0] = (_Float16)b0[kg * 8 + 0]; b00[1] = (_Float16)b0[kg * 8 + 1];
    b01[0] = (_Float16)b0[kg * 8 + 2]; b01[1] = (_Float16)b0[kg * 8 + 3];
    b02[0] = (_Float16)b0[kg * 8 + 4]; b02[1] = (_Float16)b0[kg * 8 + 5];
    b03[0] = (_Float16)b0[kg * 8 + 6]; b03[1] = (_Float16)b0[kg * 8 + 7];

    half8 a0, a1;
    #pragma unroll
    for (int i = 0; i < 8; ++i) {
        a0[i] = (_Float16)W1[(kg * 8 + i) * HID + m];
        a1[i] = (_Float16)W1[(kg * 8 + i) * HID + 16 + m];
    }
    float4v c0i, c1i;
    float w2a0, w2a1, w2a2, w2a3, w2b0, w2b1, w2b2, w2b3;
    #pragma unroll
    for (int r = 0; r < 4; ++r) {
        c0i[r] = b1[kg * 4 + r];
        c1i[r] = b1[16 + kg * 4 + r];
    }
    w2a0 = W2[kg * 4 + 0]; w2a1 = W2[kg * 4 + 1];
    w2a2 = W2[kg * 4 + 2]; w2a3 = W2[kg * 4 + 3];
    w2b0 = W2[16 + kg * 4 + 0]; w2b1 = W2[16 + kg * 4 + 1];
    w2b2 = W2[16 + kg * 4 + 2]; w2b3 = W2[16 + kg * 4 + 3];
    const float b2v = b2[0];

    // -------- wave -> one grid row --------
    const int wid = __builtin_amdgcn_readfirstlane(threadIdx.x >> 6);
    const int t   = blockIdx.y;                 // SGPR
    const int i0  = blockIdx.x * 4 + wid;       // SGPR row index
    const int sbase = i0 << 8;

    const float* __restrict__ xt   = x   + ((size_t)t << 16);
    float* __restrict__       outt = out + ((size_t)t << 16);

    // tile body: layer0(pk f16) -> 2 MFMA -> f32 elu epilogue -> masked store
    #define TILE_BODY(IN0, IN1, IN2, IN3, IN4, OUTP)                      \
    {                                                                     \
        h2 z0 = b00, z1v = b01, z2 = b02, z3 = b03;                       \
        h2 p;                                                             \
        p = splat2(IN0); z0 = p * w00 + z0; z1v = p * w01 + z1v;          \
                         z2 = p * w02 + z2; z3 = p * w03 + z3;            \
        p = splat2(IN1); z0 = p * w10 + z0; z1v = p * w11 + z1v;          \
                         z2 = p * w12 + z2; z3 = p * w13 + z3;            \
        p = splat2(IN2); z0 = p * w20 + z0; z1v = p * w21 + z1v;          \
                         z2 = p * w22 + z2; z3 = p * w23 + z3;            \
        p = splat2(IN3); z0 = p * w30 + z0; z1v = p * w31 + z1v;          \
                         z2 = p * w32 + z2; z3 = p * w33 + z3;            \
        p = splat2(IN4); z0 = p * w40 + z0; z1v = p * w41 + z1v;          \
                         z2 = p * w42 + z2; z3 = p * w43 + z3;            \
        h2 h0p = elu2(z0), h1p = elu2(z1v), h2p = elu2(z2), h3p = elu2(z3);\
        half8 hf;                                                         \
        hf[0] = h0p[0]; hf[1] = h0p[1]; hf[2] = h1p[0]; hf[3] = h1p[1];   \
        hf[4] = h2p[0]; hf[5] = h2p[1]; hf[6] = h3p[0]; hf[7] = h3p[1];   \
        float4v d0 = __builtin_amdgcn_mfma_f32_16x16x32_f16(a0, hf, c0i, 0, 0, 0); \
        float4v d1 = __builtin_amdgcn_mfma_f32_16x16x32_f16(a1, hf, c1i, 0, 0, 0); \
        float part = 0.0f;                                                \
        part = fmaf(eluf(d0[0]), w2a0, part);                             \
        part = fmaf(eluf(d0[1]), w2a1, part);                             \
        part = fmaf(eluf(d0[2]), w2a2, part);                             \
        part = fmaf(eluf(d0[3]), w2a3, part);                             \
        part = fmaf(eluf(d1[0]), w2b0, part);                             \
        part = fmaf(eluf(d1[1]), w2b1, part);                             \
        part = fmaf(eluf(d1[2]), w2b2, part);                             \
        part = fmaf(eluf(d1[3]), w2b3, part);                             \
        part += __shfl_xor(part, 16, 64);                                 \
        part += __shfl_xor(part, 32, 64);                                 \
        if (kg == 0) *(OUTP) = part + b2v;                                \
    }

    if (i0 != 0 && i0 != 255) {
        // Interior row: one per-lane base, ALL loads via immediate offsets.
        const float* __restrict__ bp = xt + sbase + m;
        const float rowwrap = xt[sbase];   // r-wrap value for (l=15, m=15)
        #pragma unroll
        for (int l = 0; l < 15; ++l) {
            const int o = 16 * l;
            TILE_BODY(bp[o - 1], bp[o - NS], bp[o], bp[o + 1], bp[o + NS],
                      outt + sbase + o + m)
        }
        {   // peeled last tile: row-periodic fix only here
            const int o = 16 * 15;
            const float in3 = (m == 15) ? rowwrap : bp[o + 1];
            TILE_BODY(bp[o - 1], bp[o - NS], bp[o], in3, bp[o + NS],
                      outt + sbase + o + m)
        }
    } else {
        // Boundary rows (i0 == 0 or 255): generic masked indices (validated).
        #pragma unroll
        for (int l = 0; l < 16; ++l) {
            const int s   = sbase + 16 * l + m;
            const int sl  = (s - 1)  & (N2 - 1);
            const int sl2 = (s - NS) & (N2 - 1);
            const int sr  = (s & ~(NS - 1)) | ((s + 1) & (NS - 1));
            const int sr2 = (s + NS) & (N2 - 1);
            TILE_BODY(xt[sl], xt[sl2], xt[s], xt[sr], xt[sr2], outt + s)
        }
    }
    #undef TILE_BODY
}

extern "C" void kernel_launch(void* const* d_in, const int* in_sizes, int n_in,
                              void* d_out, int out_size, void* d_ws, size_t ws_size,
                              hipStream_t stream) {
    const float* x  = (const float*)d_in[0];
    const float* W0 = (const float*)d_in[1];
    const float* b0 = (const float*)d_in[2];
    const float* W1 = (const float*)d_in[3];
    const float* b1 = (const float*)d_in[4];
    const float* W2 = (const float*)d_in[5];
    const float* b2 = (const float*)d_in[6];
    float* out = (float*)d_out;

    dim3 grid(NS / 4, T_STEPS);   // 64 x 64 blocks; block = 4 waves = 4 rows
    mlpconv_row_kernel<<<grid, dim3(256), 0, stream>>>(
        x, W0, b0, W1, b1, W2, b2, out);
}

// Round 7
// 127.288 us; speedup vs baseline: 1.1014x; 1.1014x over previous
//
#include <hip/hip_runtime.h>
#include <hip/hip_fp16.h>

#define NS 256
#define N2 (NS * NS)          // 65536
#define HID 32
#define T_STEPS 64

typedef _Float16 h2     __attribute__((ext_vector_type(2)));
typedef _Float16 half8  __attribute__((ext_vector_type(8)));
typedef float    float4v __attribute__((ext_vector_type(4)));

union H8 { half8 v8; h2 v2[4]; };

// cvt_pkrtz returns __fp16x2; bit-identical to our h2 (_Float16x2)
__device__ __forceinline__ h2 pk(float a, float b) {
    return __builtin_bit_cast(h2, __builtin_amdgcn_cvt_pkrtz(a, b));
}

// packed-f16 ELU: max(z, exp2(min(z,0)*log2e) - 1)
__device__ __forceinline__ h2 elu2(h2 z) {
    h2 zero; zero[0] = (_Float16)0.f; zero[1] = (_Float16)0.f;
    h2 zm  = __builtin_elementwise_min(z, zero);
    h2 e   = __builtin_elementwise_exp2(zm * (_Float16)1.442695041f);
    h2 em1 = e + (_Float16)(-1.0f);
    return __builtin_elementwise_max(z, em1);
}

__global__ __launch_bounds__(256, 4) void mlpconv_3mfma_kernel(
    const float* __restrict__ x,
    const float* __restrict__ W0, const float* __restrict__ b0,
    const float* __restrict__ W1, const float* __restrict__ b1,
    const float* __restrict__ W2, const float* __restrict__ b2,
    float* __restrict__ out)
{
    const int lane = threadIdx.x & 63;
    const int m    = lane & 15;   // point col (B col / C-D col / A row)
    const int kg   = lane >> 4;   // k-group: this lane's A/B k-slots are 8kg..8kg+7

    // Channel permutation: MFMA-even covers channel c0(row), MFMA-odd c0(row)+4,
    // chosen so lane(kg,m)'s D rows {4kg+r} are channels {8kg+r} / {8kg+4+r} —
    // i.e. D lands directly in the NEXT MFMA's B-frag layout (k = 8kg+i).
    const int c0 = 8 * (m >> 2) + (m & 3);
    const int c1 = c0 + 4;

    // ---- persistent MFMA fragments (the only long-lived registers) ----
    H8 a00, a01;          // layer-0 A = W0^T permuted, k>=5 rows zero
    #pragma unroll
    for (int i = 0; i < 8; ++i) {
        const int k = 8 * kg + i;
        a00.v8[i] = (k < 5) ? (_Float16)W0[k * HID + c0] : (_Float16)0.f;
        a01.v8[i] = (k < 5) ? (_Float16)W0[k * HID + c1] : (_Float16)0.f;
    }
    H8 a10, a11;          // layer-1 A = W1^T permuted
    #pragma unroll
    for (int i = 0; i < 8; ++i) {
        a10.v8[i] = (_Float16)W1[(8 * kg + i) * HID + c0];
        a11.v8[i] = (_Float16)W1[(8 * kg + i) * HID + c1];
    }
    H8 a2;                // layer-2 A: row 0 = W2, other rows zero
    #pragma unroll
    for (int i = 0; i < 8; ++i)
        a2.v8[i] = (m == 0) ? (_Float16)W2[8 * kg + i] : (_Float16)0.f;

    float4v cl0a, cl0b, cl1a, cl1b;   // biases pre-placed in C/D layout
    #pragma unroll
    for (int r = 0; r < 4; ++r) {
        cl0a[r] = b0[8 * kg + r];
        cl0b[r] = b0[8 * kg + 4 + r];
        cl1a[r] = b1[8 * kg + r];
        cl1b[r] = b1[8 * kg + 4 + r];
    }
    float4v c2;
    c2[0] = (kg == 0) ? b2[0] : 0.0f;
    c2[1] = 0.0f; c2[2] = 0.0f; c2[3] = 0.0f;

    // Pin fragments: opaque defs the allocator cannot rematerialize.
    asm volatile("" : "+v"(a00.v8), "+v"(a01.v8), "+v"(a10.v8), "+v"(a11.v8),
                      "+v"(a2.v8), "+v"(cl0a), "+v"(cl0b), "+v"(cl1a), "+v"(cl1b));

    // ---- wave -> one grid row; all wraps folded into bases / two cndmasks ----
    const int wid   = __builtin_amdgcn_readfirstlane(threadIdx.x >> 6);
    const int t     = blockIdx.y;
    const int i0    = blockIdx.x * 4 + wid;      // grid row (SGPR)
    const int sbase = i0 << 8;

    const float* __restrict__ xt  = x + ((size_t)t << 16);
    const float* __restrict__ xtu = xt + ((i0 == 0)      ? (N2 - NS) : -NS);
    const float* __restrict__ xtd = xt + ((i0 == NS - 1) ? -(N2 - NS) : NS);
    float* __restrict__       ob  = out + ((size_t)t << 16);

    const unsigned vc0 = (unsigned)(sbase + m);
    const unsigned vl0 = (unsigned)(sbase + m - 1);          // valid except s==0
    const unsigned vlA = (sbase + m == 0) ? (unsigned)(N2 - 1) : vl0;  // iter-0 fix
    const unsigned vr0 = (unsigned)(sbase + m + 1);
    const unsigned vrF = (m == 15) ? (unsigned)sbase : (vr0 + 240u);   // iter-15 fix

    #pragma unroll
    for (int l = 0; l < 16; ++l) {
        const unsigned o = 16u * (unsigned)l;
        // stencil channel order [l, l2, c, r, r2] == W0 rows 0..4 (validated r1-r5)
        const float in0 = xt [(l == 0)  ? vlA : (vl0 + o)];
        const float in1 = xtu[vc0 + o];
        const float in2 = xt [vc0 + o];
        const float in3 = xt [(l == 15) ? vrF : (vr0 + o)];
        const float in4 = xtd[vc0 + o];

        // B-frag for layer 0: k-slots 0..4 = inputs (kg=0 lanes), rest finite
        // filler (multiplied by A's zeros; kg>=1 lanes entirely don't-care).
        H8 bf;
        bf.v2[0] = pk(in0, in1);
        bf.v2[1] = pk(in2, in3);
        bf.v2[2] = pk(in4, in4);
        bf.v2[3] = bf.v2[2];

        // layer 0: z0 channels land as lane(kg,m): d0[r]=ch 8kg+r, d1[r]=ch 8kg+4+r
        float4v d0 = __builtin_amdgcn_mfma_f32_16x16x32_f16(a00.v8, bf.v8, cl0a, 0, 0, 0);
        float4v d1 = __builtin_amdgcn_mfma_f32_16x16x32_f16(a01.v8, bf.v8, cl0b, 0, 0, 0);

        // ELU + pack: result IS the layer-1 B-frag (channels 8kg..8kg+7)
        H8 hf;
        hf.v2[0] = elu2(pk(d0[0], d0[1]));
        hf.v2[1] = elu2(pk(d0[2], d0[3]));
        hf.v2[2] = elu2(pk(d1[0], d1[1]));
        hf.v2[3] = elu2(pk(d1[2], d1[3]));

        // layer 1
        float4v e0 = __builtin_amdgcn_mfma_f32_16x16x32_f16(a10.v8, hf.v8, cl1a, 0, 0, 0);
        float4v e1 = __builtin_amdgcn_mfma_f32_16x16x32_f16(a11.v8, hf.v8, cl1b, 0, 0, 0);

        // ELU + pack: layer-2 B-frag
        H8 gf;
        gf.v2[0] = elu2(pk(e0[0], e0[1]));
        gf.v2[1] = elu2(pk(e0[2], e0[3]));
        gf.v2[2] = elu2(pk(e1[0], e1[1]));
        gf.v2[3] = elu2(pk(e1[2], e1[3]));

        // layer 2: D row 0 (kg==0, r==0) = b2 + sum_k W2[k]*gf[k]
        float4v dz = __builtin_amdgcn_mfma_f32_16x16x32_f16(a2.v8, gf.v8, c2, 0, 0, 0);

        if (kg == 0) ob[vc0 + o] = dz[0];
    }
}

extern "C" void kernel_launch(void* const* d_in, const int* in_sizes, int n_in,
                              void* d_out, int out_size, void* d_ws, size_t ws_size,
                              hipStream_t stream) {
    const float* x  = (const float*)d_in[0];
    const float* W0 = (const float*)d_in[1];
    const float* b0 = (const float*)d_in[2];
    const float* W1 = (const float*)d_in[3];
    const float* b1 = (const float*)d_in[4];
    const float* W2 = (const float*)d_in[5];
    const float* b2 = (const float*)d_in[6];
    float* out = (float*)d_out;

    dim3 grid(NS / 4, T_STEPS);   // 64 x 64 blocks; block = 4 waves = 4 rows
    mlpconv_3mfma_kernel<<<grid, dim3(256), 0, stream>>>(
        x, W0, b0, W1, b1, W2, b2, out);
}